// Round 1
// baseline (332.422 us; speedup 1.0000x reference)
//
#include <hip/hip_runtime.h>
#include <hip/hip_bf16.h>

// Problem constants
#define Bc   2
#define Nc   4096
#define Hc   4
#define HIDc 256
#define VDc  64

typedef short s8v  __attribute__((ext_vector_type(8)));
typedef float f4v  __attribute__((ext_vector_type(4)));

// ---------------------------------------------------------------------------
// K1: V[b,h,n,k] = sum_j x[b,n,j] * W[h,j,k]; store TRANSPOSED as VT[b,h,k,n] bf16
// grid = B*H*(N/64) = 512 blocks, 256 threads
// ---------------------------------------------------------------------------
__global__ __launch_bounds__(256) void value_kernel(
    const float* __restrict__ x, const float* __restrict__ wgt,
    unsigned short* __restrict__ vt_g)
{
    __shared__ float xs[64 * HIDc];          // 64 KB: x tile (64 rows x 256)
    __shared__ unsigned short ob[64 * 64];   // 8 KB: out tile [k][n] bf16

    int t  = threadIdx.x;
    int bid = blockIdx.x;
    int nt = bid & 63;
    int h  = (bid >> 6) & 3;
    int b  = bid >> 8;
    int n0 = nt * 64;

    const float* xg = x + ((size_t)b * Nc + n0) * HIDc;
    #pragma unroll
    for (int i = 0; i < 16; i++)
        ((float4*)xs)[t + i * 256] = ((const float4*)xg)[t + i * 256];
    __syncthreads();

    int k4 = t & 15;      // float4-group of k (k = k4*4 .. +3)
    int ns = t >> 4;      // n sub-row
    const float4* wg4 = (const float4*)(wgt + (size_t)h * HIDc * VDc);

    float acc[4][4];
    #pragma unroll
    for (int i = 0; i < 4; i++)
        #pragma unroll
        for (int c = 0; c < 4; c++) acc[i][c] = 0.0f;

    for (int j = 0; j < HIDc; j++) {
        float4 wv = wg4[j * 16 + k4];        // W[h][j][k4*4..+3], coalesced
        #pragma unroll
        for (int i = 0; i < 4; i++) {
            float xv = xs[(ns + i * 16) * HIDc + j];  // LDS broadcast
            acc[i][0] += xv * wv.x;
            acc[i][1] += xv * wv.y;
            acc[i][2] += xv * wv.z;
            acc[i][3] += xv * wv.w;
        }
    }
    #pragma unroll
    for (int i = 0; i < 4; i++) {
        int nn = ns + i * 16;
        #pragma unroll
        for (int c = 0; c < 4; c++) {
            __hip_bfloat16 hb = __float2bfloat16(acc[i][c]);
            ob[(k4 * 4 + c) * 64 + nn] = *(unsigned short*)&hb;
        }
    }
    __syncthreads();

    unsigned short* vg = vt_g + (((size_t)b * Hc + h) * VDc) * Nc + n0;
    #pragma unroll
    for (int i = 0; i < 16; i++) {
        int idx = t + i * 256;
        int kk = idx >> 6, nn = idx & 63;
        vg[(size_t)kk * Nc + nn] = ob[idx];   // coalesced over nn
    }
}

// ---------------------------------------------------------------------------
// K2: per-row exact 30th percentile (linear interp => midpoint of ranks 1228/1229)
// plus row min. Mask is head-independent since scaled = m_dist * r^2 (r^2 >= 0,
// monotone), so threshold on raw m_dist. grid = B*N = 8192 blocks, 256 threads.
// ---------------------------------------------------------------------------
__global__ __launch_bounds__(256) void thresh_kernel(
    const float* __restrict__ m_dist,
    float* __restrict__ thr_out, float* __restrict__ min_out)
{
    __shared__ unsigned int hist[1024];
    __shared__ float wred[4];
    __shared__ unsigned int wscan[4];
    __shared__ int b0s, b1s;
    __shared__ unsigned int c0s;
    __shared__ unsigned int ncand;
    __shared__ float cand[256];
    __shared__ float s0s, s1s;

    int t = threadIdx.x;
    size_t rowid = blockIdx.x;
    const float* row = m_dist + rowid * Nc;

    for (int i = t; i < 1024; i += 256) hist[i] = 0u;
    if (t == 0) ncand = 0u;
    __syncthreads();

    float4 vals[4];
    float lmin = 1e30f;
    #pragma unroll
    for (int i = 0; i < 4; i++) {
        float4 v = ((const float4*)row)[t + i * 256];
        vals[i] = v;
        lmin = fminf(lmin, fminf(fminf(v.x, v.y), fminf(v.z, v.w)));
        atomicAdd(&hist[min(1023, (int)(v.x * 1024.0f))], 1u);
        atomicAdd(&hist[min(1023, (int)(v.y * 1024.0f))], 1u);
        atomicAdd(&hist[min(1023, (int)(v.z * 1024.0f))], 1u);
        atomicAdd(&hist[min(1023, (int)(v.w * 1024.0f))], 1u);
    }
    // min reduce
    #pragma unroll
    for (int o = 32; o > 0; o >>= 1) lmin = fminf(lmin, __shfl_xor(lmin, o));
    if ((t & 63) == 0) wred[t >> 6] = lmin;
    __syncthreads();
    float rmin = fminf(fminf(wred[0], wred[1]), fminf(wred[2], wred[3]));

    // scan: thread t owns bins 4t..4t+3
    unsigned int c[4], csum = 0;
    #pragma unroll
    for (int j = 0; j < 4; j++) { c[j] = hist[t * 4 + j]; csum += c[j]; }
    unsigned int inc = csum;
    #pragma unroll
    for (int o = 1; o < 64; o <<= 1) {
        unsigned int nv = __shfl_up(inc, o);
        if ((t & 63) >= o) inc += nv;
    }
    if ((t & 63) == 63) wscan[t >> 6] = inc;
    __syncthreads();
    unsigned int wpref = 0;
    for (int wv = 0; wv < (t >> 6); wv++) wpref += wscan[wv];
    unsigned int P = wpref + inc - csum;    // values in bins < 4t

    const unsigned int R0 = 1228u, R1 = 1229u;   // 0-indexed order stats
    unsigned int cum = P;
    #pragma unroll
    for (int j = 0; j < 4; j++) {
        unsigned int lo = cum, hi = cum + c[j];
        if (R0 >= lo && R0 < hi) { b0s = t * 4 + j; c0s = lo; }
        if (R1 >= lo && R1 < hi) { b1s = t * 4 + j; }
        cum = hi;
    }
    __syncthreads();
    int b0 = b0s, b1 = b1s;
    unsigned int C0 = c0s;

    // gather candidates in bins [b0, b1]
    #pragma unroll
    for (int i = 0; i < 4; i++) {
        float a[4] = {vals[i].x, vals[i].y, vals[i].z, vals[i].w};
        #pragma unroll
        for (int j = 0; j < 4; j++) {
            int bx = min(1023, (int)(a[j] * 1024.0f));
            if (bx >= b0 && bx <= b1) {
                unsigned int p = atomicAdd(&ncand, 1u);
                if (p < 256u) cand[p] = a[j];
            }
        }
    }
    __syncthreads();
    unsigned int nc = min(ncand, 256u);
    if ((unsigned int)t < nc) {
        float v = cand[t];
        unsigned int rk = C0;
        for (unsigned int j = 0; j < nc; j++) {
            float u = cand[j];
            rk += (u < v || (u == v && j < (unsigned int)t)) ? 1u : 0u;
        }
        if (rk == R0) s0s = v;
        if (rk == R1) s1s = v;
    }
    __syncthreads();
    if (t == 0) {
        thr_out[rowid] = 0.5f * (s0s + s1s);  // any value in [s0,s1) gives same mask
        min_out[rowid] = rmin;
    }
}

// ---------------------------------------------------------------------------
// K3: fused mask + softmax + PV (bf16 MFMA) + GELU.
// grid = B*(N/16) = 512 blocks, 256 threads (4 waves; wave id = head).
// 16 attention rows per block; j tiled by 64.
// ---------------------------------------------------------------------------
#define NT 16
#define JT 64
#define MPAD 68   // m tile row stride (f32), +16B pad
#define WPAD 72   // w/vt tile row stride (bf16), +16B pad (144B = 9*16)

__global__ __launch_bounds__(256) void attn_kernel(
    const float* __restrict__ m_dist, const float* __restrict__ rr,
    const unsigned short* __restrict__ vt_g,
    const float* __restrict__ thr_g, const float* __restrict__ min_g,
    float* __restrict__ out)
{
    __shared__ float ms[NT * MPAD];                 // 4.25 KB
    __shared__ unsigned short wt[Hc * NT * WPAD];   // 9 KB   [h][row][j]
    __shared__ unsigned short vt[Hc * VDc * WPAD];  // 36 KB  [h][k][j]
    __shared__ float Zl[NT * Hc];
    __shared__ float thr_s[NT], min_s[NT];

    int t = threadIdx.x;
    int b = blockIdx.x >> 8;
    int n0 = (blockIdx.x & 255) * NT;

    if (t < NT) {
        thr_s[t] = thr_g[b * Nc + n0 + t];
        min_s[t] = min_g[b * Nc + n0 + t];
    }
    float cexp[4];
    #pragma unroll
    for (int h = 0; h < 4; h++) {
        float rv = rr[h];
        cexp[h] = -(rv * rv) * 1.4426950408889634f;  // -r^2 * log2(e)
    }

    int lane = t & 63, q = lane >> 4, m16 = lane & 15;
    int hw = t >> 6;              // wave id = head
    int wrow = t >> 4, wjg = t & 15;  // w-compute mapping: row, j-group of 4

    f4v acc[4];
    #pragma unroll
    for (int ct = 0; ct < 4; ct++) acc[ct] = (f4v){0.f, 0.f, 0.f, 0.f};
    float zacc[4] = {0.f, 0.f, 0.f, 0.f};

    const float* mbase = m_dist + ((size_t)b * Nc + n0) * Nc;
    const unsigned short* vtb = vt_g + ((size_t)b * Hc * VDc) * Nc;

    for (int jt = 0; jt < Nc; jt += JT) {
        // --- stage m tile (16x64 f32): 1 float4/thread ---
        {
            int row = t >> 4, ch = t & 15;
            float4 v = *(const float4*)(mbase + (size_t)row * Nc + jt + ch * 4);
            *(float4*)&ms[row * MPAD + ch * 4] = v;
        }
        // --- stage VT tiles (4 heads x 64 k x 64 j bf16): 8 float4/thread ---
        #pragma unroll
        for (int i = 0; i < 8; i++) {
            int cid = t + i * 256;
            int rrow = cid >> 3, ch = cid & 7;   // rrow = h*64 + k
            float4 v = *(const float4*)(vtb + (size_t)rrow * Nc + jt + ch * 8);
            *(float4*)&vt[rrow * WPAD + ch * 8] = v;
        }
        __syncthreads();

        // --- w tiles: w = (d<=thr) ? exp2((d-min)*cexp[h]) : 0, bf16 ---
        {
            float4 dv = *(const float4*)&ms[wrow * MPAD + wjg * 4];
            float th = thr_s[wrow], mn = min_s[wrow];
            float d0 = dv.x - mn, d1 = dv.y - mn, d2 = dv.z - mn, d3 = dv.w - mn;
            bool k0 = dv.x <= th, k1 = dv.y <= th, k2 = dv.z <= th, k3 = dv.w <= th;
            #pragma unroll
            for (int h = 0; h < 4; h++) {
                float cc = cexp[h];
                float w0 = k0 ? __builtin_amdgcn_exp2f(d0 * cc) : 0.0f;
                float w1 = k1 ? __builtin_amdgcn_exp2f(d1 * cc) : 0.0f;
                float w2 = k2 ? __builtin_amdgcn_exp2f(d2 * cc) : 0.0f;
                float w3 = k3 ? __builtin_amdgcn_exp2f(d3 * cc) : 0.0f;
                zacc[h] += (w0 + w1) + (w2 + w3);
                __hip_bfloat16 h0 = __float2bfloat16(w0), h1 = __float2bfloat16(w1);
                __hip_bfloat16 h2 = __float2bfloat16(w2), h3 = __float2bfloat16(w3);
                unsigned int lo = (unsigned int)*(unsigned short*)&h0 |
                                  ((unsigned int)*(unsigned short*)&h1 << 16);
                unsigned int hi = (unsigned int)*(unsigned short*)&h2 |
                                  ((unsigned int)*(unsigned short*)&h3 << 16);
                uint2 pk = {lo, hi};
                *(uint2*)&wt[(h * NT + wrow) * WPAD + wjg * 4] = pk;
            }
        }
        __syncthreads();

        // --- MFMA: wave hw computes 16 rows x 64 cols for head hw ---
        {
            const unsigned short* wb = &wt[(hw * NT + m16) * WPAD];
            const unsigned short* vb = &vt[(hw * VDc) * WPAD];
            #pragma unroll
            for (int ks = 0; ks < 2; ks++) {
                s8v af = *(const s8v*)(wb + ks * 32 + q * 8);  // A[m=m16][k=q*8+j]
                #pragma unroll
                for (int ct = 0; ct < 4; ct++) {
                    s8v bf = *(const s8v*)(vb + (ct * 16 + m16) * WPAD + ks * 32 + q * 8);
                    acc[ct] = __builtin_amdgcn_mfma_f32_16x16x32_bf16(af, bf, acc[ct], 0, 0, 0);
                }
            }
        }
        __syncthreads();
    }

    // --- Z: reduce over the 16 lanes sharing wrow ---
    #pragma unroll
    for (int h = 0; h < 4; h++) {
        float z = zacc[h];
        z += __shfl_xor(z, 1); z += __shfl_xor(z, 2);
        z += __shfl_xor(z, 4); z += __shfl_xor(z, 8);
        if (wjg == 0) Zl[wrow * Hc + h] = z;
    }
    __syncthreads();

    // --- epilogue: normalize, exact GELU, store (b,n,h*64+k) ---
    #pragma unroll
    for (int ct = 0; ct < 4; ct++) {
        #pragma unroll
        for (int rg = 0; rg < 4; rg++) {
            int nl = q * 4 + rg;                   // D row = quad*4 + reg
            float z = Zl[nl * Hc + hw];
            float v = acc[ct][rg] / z;
            float g = 0.5f * v * (1.0f + erff(v * 0.7071067811865476f));
            out[((size_t)b * Nc + n0 + nl) * HIDc + hw * VDc + ct * 16 + m16] = g;
        }
    }
}

// ---------------------------------------------------------------------------
extern "C" void kernel_launch(void* const* d_in, const int* in_sizes, int n_in,
                              void* d_out, int out_size, void* d_ws, size_t ws_size,
                              hipStream_t stream) {
    const float* m_dist = (const float*)d_in[0];
    const float* x      = (const float*)d_in[1];
    const float* r      = (const float*)d_in[2];
    const float* weight = (const float*)d_in[3];
    float* out = (float*)d_out;

    char* ws = (char*)d_ws;
    unsigned short* vt = (unsigned short*)ws;                       // 4 MB bf16 VT
    float* thr = (float*)(ws + (size_t)4 * 1024 * 1024);            // 32 KB
    float* mn  = (float*)(ws + (size_t)4 * 1024 * 1024 + 32 * 1024);// 32 KB

    value_kernel<<<512, 256, 0, stream>>>(x, weight, vt);
    thresh_kernel<<<Bc * Nc, 256, 0, stream>>>(m_dist, thr, mn);
    attn_kernel<<<Bc * (Nc / NT), 256, 0, stream>>>(m_dist, r, vt, thr, mn, out);
}

// Round 2
// 296.045 us; speedup vs baseline: 1.1229x; 1.1229x over previous
//
#include <hip/hip_runtime.h>
#include <hip/hip_bf16.h>

// Problem constants
#define Bc   2
#define Nc   4096
#define Hc   4
#define HIDc 256
#define VDc  64

typedef short s8v  __attribute__((ext_vector_type(8)));
typedef float f4v  __attribute__((ext_vector_type(4)));

// ---------------------------------------------------------------------------
// K1: V[b,h,n,k] = sum_j x[b,n,j] * W[h,j,k]; store TRANSPOSED as VT[b,h,k,n] bf16
// grid = B*H*(N/64) = 512 blocks, 256 threads
// ---------------------------------------------------------------------------
__global__ __launch_bounds__(256) void value_kernel(
    const float* __restrict__ x, const float* __restrict__ wgt,
    unsigned short* __restrict__ vt_g)
{
    __shared__ float xs[64 * HIDc];          // 64 KB: x tile (64 rows x 256)
    __shared__ unsigned short ob[64 * 64];   // 8 KB: out tile [k][n] bf16

    int t  = threadIdx.x;
    int bid = blockIdx.x;
    int nt = bid & 63;
    int h  = (bid >> 6) & 3;
    int b  = bid >> 8;
    int n0 = nt * 64;

    const float* xg = x + ((size_t)b * Nc + n0) * HIDc;
    #pragma unroll
    for (int i = 0; i < 16; i++)
        ((float4*)xs)[t + i * 256] = ((const float4*)xg)[t + i * 256];
    __syncthreads();

    int k4 = t & 15;      // float4-group of k (k = k4*4 .. +3)
    int ns = t >> 4;      // n sub-row
    const float4* wg4 = (const float4*)(wgt + (size_t)h * HIDc * VDc);

    float acc[4][4];
    #pragma unroll
    for (int i = 0; i < 4; i++)
        #pragma unroll
        for (int c = 0; c < 4; c++) acc[i][c] = 0.0f;

    for (int j = 0; j < HIDc; j++) {
        float4 wv = wg4[j * 16 + k4];        // W[h][j][k4*4..+3], coalesced
        #pragma unroll
        for (int i = 0; i < 4; i++) {
            float xv = xs[(ns + i * 16) * HIDc + j];  // LDS broadcast
            acc[i][0] += xv * wv.x;
            acc[i][1] += xv * wv.y;
            acc[i][2] += xv * wv.z;
            acc[i][3] += xv * wv.w;
        }
    }
    #pragma unroll
    for (int i = 0; i < 4; i++) {
        int nn = ns + i * 16;
        #pragma unroll
        for (int c = 0; c < 4; c++) {
            __hip_bfloat16 hb = __float2bfloat16(acc[i][c]);
            ob[(k4 * 4 + c) * 64 + nn] = *(unsigned short*)&hb;
        }
    }
    __syncthreads();

    unsigned short* vg = vt_g + (((size_t)b * Hc + h) * VDc) * Nc + n0;
    #pragma unroll
    for (int i = 0; i < 16; i++) {
        int idx = t + i * 256;
        int kk = idx >> 6, nn = idx & 63;
        vg[(size_t)kk * Nc + nn] = ob[idx];   // coalesced over nn
    }
}

// ---------------------------------------------------------------------------
// K2: per-row exact 30th percentile (ranks 1228/1229) + row min.
// Mask is head-independent (scaled = m_dist*r^2, monotone). 8192 blocks x 256.
// ---------------------------------------------------------------------------
__global__ __launch_bounds__(256) void thresh_kernel(
    const float* __restrict__ m_dist,
    float* __restrict__ thr_out, float* __restrict__ min_out)
{
    __shared__ unsigned int hist[1024];
    __shared__ float wred[4];
    __shared__ unsigned int wscan[4];
    __shared__ int b0s, b1s;
    __shared__ unsigned int c0s;
    __shared__ unsigned int ncand;
    __shared__ float cand[256];
    __shared__ float s0s, s1s;

    int t = threadIdx.x;
    size_t rowid = blockIdx.x;
    const float* row = m_dist + rowid * Nc;

    for (int i = t; i < 1024; i += 256) hist[i] = 0u;
    if (t == 0) ncand = 0u;
    __syncthreads();

    float4 vals[4];
    float lmin = 1e30f;
    #pragma unroll
    for (int i = 0; i < 4; i++) {
        float4 v = ((const float4*)row)[t + i * 256];
        vals[i] = v;
        lmin = fminf(lmin, fminf(fminf(v.x, v.y), fminf(v.z, v.w)));
        atomicAdd(&hist[min(1023, (int)(v.x * 1024.0f))], 1u);
        atomicAdd(&hist[min(1023, (int)(v.y * 1024.0f))], 1u);
        atomicAdd(&hist[min(1023, (int)(v.z * 1024.0f))], 1u);
        atomicAdd(&hist[min(1023, (int)(v.w * 1024.0f))], 1u);
    }
    // min reduce
    #pragma unroll
    for (int o = 32; o > 0; o >>= 1) lmin = fminf(lmin, __shfl_xor(lmin, o));
    if ((t & 63) == 0) wred[t >> 6] = lmin;
    __syncthreads();
    float rmin = fminf(fminf(wred[0], wred[1]), fminf(wred[2], wred[3]));

    // scan: thread t owns bins 4t..4t+3
    unsigned int c[4], csum = 0;
    #pragma unroll
    for (int j = 0; j < 4; j++) { c[j] = hist[t * 4 + j]; csum += c[j]; }
    unsigned int inc = csum;
    #pragma unroll
    for (int o = 1; o < 64; o <<= 1) {
        unsigned int nv = __shfl_up(inc, o);
        if ((t & 63) >= o) inc += nv;
    }
    if ((t & 63) == 63) wscan[t >> 6] = inc;
    __syncthreads();
    unsigned int wpref = 0;
    for (int wv = 0; wv < (t >> 6); wv++) wpref += wscan[wv];
    unsigned int P = wpref + inc - csum;    // values in bins < 4t

    const unsigned int R0 = 1228u, R1 = 1229u;   // 0-indexed order stats
    unsigned int cum = P;
    #pragma unroll
    for (int j = 0; j < 4; j++) {
        unsigned int lo = cum, hi = cum + c[j];
        if (R0 >= lo && R0 < hi) { b0s = t * 4 + j; c0s = lo; }
        if (R1 >= lo && R1 < hi) { b1s = t * 4 + j; }
        cum = hi;
    }
    __syncthreads();
    int b0 = b0s, b1 = b1s;
    unsigned int C0 = c0s;

    // gather candidates in bins [b0, b1]
    #pragma unroll
    for (int i = 0; i < 4; i++) {
        float a[4] = {vals[i].x, vals[i].y, vals[i].z, vals[i].w};
        #pragma unroll
        for (int j = 0; j < 4; j++) {
            int bx = min(1023, (int)(a[j] * 1024.0f));
            if (bx >= b0 && bx <= b1) {
                unsigned int p = atomicAdd(&ncand, 1u);
                if (p < 256u) cand[p] = a[j];
            }
        }
    }
    __syncthreads();
    unsigned int nc = min(ncand, 256u);
    if ((unsigned int)t < nc) {
        float v = cand[t];
        unsigned int rk = C0;
        for (unsigned int j = 0; j < nc; j++) {
            float u = cand[j];
            rk += (u < v || (u == v && j < (unsigned int)t)) ? 1u : 0u;
        }
        if (rk == R0) s0s = v;
        if (rk == R1) s1s = v;
    }
    __syncthreads();
    if (t == 0) {
        thr_out[rowid] = 0.5f * (s0s + s1s);  // any value in [s0,s1) gives same mask
        min_out[rowid] = rmin;
    }
}

// ---------------------------------------------------------------------------
// K3: fused mask + softmax-numerator + PV (bf16 MFMA), split-K over j.
// grid = S * B * (N/32) blocks, 512 threads (8 waves: wave = (rowhalf, head)).
// A-fragments (w) computed IN-REGISTER by their consuming lane — no wt LDS,
// 2 barriers/iter. Partial O (unnormalized) + partial Z to workspace.
// ---------------------------------------------------------------------------
#define NT 32
#define JT 64
#define MPAD 68   // ms row stride (f32): 4-bank offset/row -> 2-way max (free)
#define WPAD 72   // vt row stride (bf16): 2-way max per 16-lane phase (free)

__global__ __launch_bounds__(512, 6) void attn_kernel(
    const float* __restrict__ m_dist, const float* __restrict__ rr,
    const unsigned short* __restrict__ vt_g,
    const float* __restrict__ thr_g, const float* __restrict__ min_g,
    float* __restrict__ Op, float* __restrict__ Zp, int jlen)
{
    __shared__ float ms[NT * MPAD];                 // 8.7 KB
    __shared__ unsigned short vt[Hc * VDc * WPAD];  // 36.9 KB

    int t = threadIdx.x;
    const int nblk = Bc * (Nc / NT);        // 256
    int js = blockIdx.x / nblk;
    int rb = blockIdx.x - js * nblk;
    int b  = rb >> 7;                       // Nc/NT = 128 row-tiles
    int n0 = (rb & 127) * NT;
    int j0 = js * jlen;

    int lane = t & 63, q = lane >> 4, m16 = lane & 15;
    int w = t >> 6;                         // wave 0..7
    int h = w & 3, rh = w >> 2;
    int row = rh * 16 + m16;                // local A-row this lane owns

    float th = thr_g[b * Nc + n0 + row];
    float mn = min_g[b * Nc + n0 + row];
    float rv = rr[h];
    float cc = -(rv * rv) * 1.4426950408889634f;   // -r^2 * log2(e)

    f4v acc[4];
    #pragma unroll
    for (int ct = 0; ct < 4; ct++) acc[ct] = (f4v){0.f, 0.f, 0.f, 0.f};
    float zacc = 0.f;

    const float* mbase = m_dist + ((size_t)b * Nc + n0) * Nc + j0;
    const unsigned short* vtb = vt_g + ((size_t)b * Hc * VDc) * Nc + j0;

    for (int jt = 0; jt < jlen; jt += JT) {
        // stage ms (32 x 64 f32): 1 float4/thread
        {
            int r_ = t >> 4, ch = t & 15;
            *(float4*)&ms[r_ * MPAD + ch * 4] =
                *(const float4*)(mbase + (size_t)r_ * Nc + jt + ch * 4);
        }
        // stage vt (4h x 64k x 64j bf16): 4 float4/thread
        #pragma unroll
        for (int i = 0; i < 4; i++) {
            int cid = t + i * 512;
            int rrow = cid >> 3, ch = cid & 7;      // rrow = h*64+k
            *(float4*)&vt[rrow * WPAD + ch * 8] =
                *(const float4*)(vtb + (size_t)rrow * Nc + jt + ch * 8);
        }
        __syncthreads();

        const unsigned short* vb = &vt[(h * VDc) * WPAD];
        #pragma unroll
        for (int ks = 0; ks < 2; ks++) {
            // A-fragment in-register: w[row][j = ks*32 + q*8 + 0..7]
            float4 a0 = *(const float4*)&ms[row * MPAD + ks * 32 + q * 8];
            float4 a1 = *(const float4*)&ms[row * MPAD + ks * 32 + q * 8 + 4];
            float w0 = (a0.x <= th) ? __builtin_amdgcn_exp2f((a0.x - mn) * cc) : 0.f;
            float w1 = (a0.y <= th) ? __builtin_amdgcn_exp2f((a0.y - mn) * cc) : 0.f;
            float w2 = (a0.z <= th) ? __builtin_amdgcn_exp2f((a0.z - mn) * cc) : 0.f;
            float w3 = (a0.w <= th) ? __builtin_amdgcn_exp2f((a0.w - mn) * cc) : 0.f;
            float w4 = (a1.x <= th) ? __builtin_amdgcn_exp2f((a1.x - mn) * cc) : 0.f;
            float w5 = (a1.y <= th) ? __builtin_amdgcn_exp2f((a1.y - mn) * cc) : 0.f;
            float w6 = (a1.z <= th) ? __builtin_amdgcn_exp2f((a1.z - mn) * cc) : 0.f;
            float w7 = (a1.w <= th) ? __builtin_amdgcn_exp2f((a1.w - mn) * cc) : 0.f;
            zacc += ((w0 + w1) + (w2 + w3)) + ((w4 + w5) + (w6 + w7));
            union { unsigned short s[8]; s8v v; } afu;
            __hip_bfloat16 hb;
            hb = __float2bfloat16(w0); afu.s[0] = *(unsigned short*)&hb;
            hb = __float2bfloat16(w1); afu.s[1] = *(unsigned short*)&hb;
            hb = __float2bfloat16(w2); afu.s[2] = *(unsigned short*)&hb;
            hb = __float2bfloat16(w3); afu.s[3] = *(unsigned short*)&hb;
            hb = __float2bfloat16(w4); afu.s[4] = *(unsigned short*)&hb;
            hb = __float2bfloat16(w5); afu.s[5] = *(unsigned short*)&hb;
            hb = __float2bfloat16(w6); afu.s[6] = *(unsigned short*)&hb;
            hb = __float2bfloat16(w7); afu.s[7] = *(unsigned short*)&hb;
            #pragma unroll
            for (int ct = 0; ct < 4; ct++) {
                s8v bf = *(const s8v*)(vb + (ct * 16 + m16) * WPAD + ks * 32 + q * 8);
                acc[ct] = __builtin_amdgcn_mfma_f32_16x16x32_bf16(afu.v, bf, acc[ct], 0, 0, 0);
            }
        }
        __syncthreads();
    }

    // Z: lanes sharing m16 across q (xor 16, 32)
    zacc += __shfl_xor(zacc, 16);
    zacc += __shfl_xor(zacc, 32);
    if (q == 0)
        Zp[(((size_t)js * Bc + b) * Hc + h) * Nc + n0 + row] = zacc;

    // partial O: D row = q*4+rg (within the 16), col = ct*16+m16
    #pragma unroll
    for (int ct = 0; ct < 4; ct++) {
        #pragma unroll
        for (int rg = 0; rg < 4; rg++) {
            int nl = rh * 16 + q * 4 + rg;
            Op[(((size_t)js * Bc + b) * Nc + n0 + nl) * HIDc + h * VDc + ct * 16 + m16]
                = acc[ct][rg];
        }
    }
}

// ---------------------------------------------------------------------------
// K4: combine split-K partials, normalize, exact GELU. f32x4 per thread.
// grid = B*N*HID/1024 = 2048 blocks x 256.
// ---------------------------------------------------------------------------
__global__ __launch_bounds__(256) void combine_kernel(
    const float* __restrict__ Op, const float* __restrict__ Zp,
    float* __restrict__ out, int S)
{
    int g = blockIdx.x * 256 + threadIdx.x;       // float4 index
    int c4 = g & 63;
    int n  = (g >> 6) & (Nc - 1);
    int b  = g >> 18;                             // 64 * 4096 = 2^18
    int h  = c4 >> 4;

    float z = 0.f;
    float4 v = {0.f, 0.f, 0.f, 0.f};
    for (int s = 0; s < S; s++) {
        z += Zp[(((size_t)s * Bc + b) * Hc + h) * Nc + n];
        float4 p = *(const float4*)&Op[(((size_t)s * Bc + b) * Nc + n) * HIDc + c4 * 4];
        v.x += p.x; v.y += p.y; v.z += p.z; v.w += p.w;
    }
    float iz = 1.0f / z;
    float4 o;
    float u;
    u = v.x * iz; o.x = 0.5f * u * (1.0f + erff(u * 0.7071067811865476f));
    u = v.y * iz; o.y = 0.5f * u * (1.0f + erff(u * 0.7071067811865476f));
    u = v.z * iz; o.z = 0.5f * u * (1.0f + erff(u * 0.7071067811865476f));
    u = v.w * iz; o.w = 0.5f * u * (1.0f + erff(u * 0.7071067811865476f));
    *(float4*)&out[(((size_t)b * Nc + n) * HIDc) + c4 * 4] = o;
}

// ---------------------------------------------------------------------------
extern "C" void kernel_launch(void* const* d_in, const int* in_sizes, int n_in,
                              void* d_out, int out_size, void* d_ws, size_t ws_size,
                              hipStream_t stream) {
    const float* m_dist = (const float*)d_in[0];
    const float* x      = (const float*)d_in[1];
    const float* r      = (const float*)d_in[2];
    const float* weight = (const float*)d_in[3];
    float* out = (float*)d_out;

    char* ws = (char*)d_ws;
    const size_t MB = 1024 * 1024;
    unsigned short* vt = (unsigned short*)ws;            // 4 MiB bf16 VT
    float* thr = (float*)(ws + 4 * MB);                  // 32 KiB
    float* mn  = (float*)(ws + 4 * MB + 32 * 1024);      // 32 KiB
    float* Zp  = (float*)(ws + 4 * MB + 64 * 1024);      // up to 512 KiB
    float* Op  = (float*)(ws + 5 * MB);                  // S * 8 MiB

    // split factor: prefer 4 (needs 37 MiB ws), else 2, else 1
    int S = 4;
    if (ws_size < 5 * MB + 4 * (size_t)(Bc * Nc * HIDc * 4)) S = 2;
    if (ws_size < 5 * MB + 2 * (size_t)(Bc * Nc * HIDc * 4)) S = 1;
    int jlen = Nc / S;

    value_kernel<<<512, 256, 0, stream>>>(x, weight, vt);
    thresh_kernel<<<Bc * Nc, 256, 0, stream>>>(m_dist, thr, mn);
    attn_kernel<<<S * Bc * (Nc / NT), 512, 0, stream>>>(m_dist, r, vt, thr, mn, Op, Zp, jlen);
    combine_kernel<<<(Bc * Nc * HIDc) / 1024, 256, 0, stream>>>(Op, Zp, out, S);
}